// Round 2
// baseline (969.687 us; speedup 1.0000x reference)
//
#include <hip/hip_runtime.h>

#define D 128

// ---------------- CSR build step 1: histogram ----------------
__global__ __launch_bounds__(256) void hist_kernel(const int* __restrict__ erow,
                                                   int* __restrict__ deg, int nE) {
    int e = blockIdx.x * 256 + threadIdx.x;
    if (e < nE) atomicAdd(&deg[erow[e]], 1);
}

// ---------------- CSR build step 2: exclusive scan (single block) ----------------
__global__ __launch_bounds__(1024) void scan_kernel(const int* __restrict__ deg,
                                                    int* __restrict__ rowptr, int n) {
    __shared__ int sdata[1024];
    __shared__ int s_running;
    if (threadIdx.x == 0) { s_running = 0; rowptr[0] = 0; }
    __syncthreads();
    for (int base = 0; base < n; base += 1024) {
        int i = base + threadIdx.x;
        int v = (i < n) ? deg[i] : 0;
        sdata[threadIdx.x] = v;
        __syncthreads();
        for (int off = 1; off < 1024; off <<= 1) {
            int t_ = (threadIdx.x >= off) ? sdata[threadIdx.x - off] : 0;
            __syncthreads();
            sdata[threadIdx.x] += t_;
            __syncthreads();
        }
        if (i < n) rowptr[i + 1] = s_running + sdata[threadIdx.x];
        __syncthreads();
        if (threadIdx.x == 0) s_running += sdata[1023];
        __syncthreads();
    }
}

// ---------------- CSR build step 3: placement (slot order nondeterministic) ----------------
__global__ __launch_bounds__(256) void place_kernel(const int* __restrict__ erow,
                                                    const int* __restrict__ rowptr,
                                                    int* __restrict__ fill,
                                                    int* __restrict__ slots, int nE) {
    int e = blockIdx.x * 256 + threadIdx.x;
    if (e >= nE) return;
    int r = erow[e];
    int pos = rowptr[r] + atomicAdd(&fill[r], 1);
    slots[pos] = e;   // store edge index for canonical re-sort
}

// ---------------- CSR build step 4: canonicalize (sort each row's slots by edge idx) ----------------
__global__ __launch_bounds__(256) void sortrow_kernel(const int* __restrict__ rowptr,
                                                      int* __restrict__ slots, int n) {
    int row = blockIdx.x * 256 + threadIdx.x;
    if (row >= n) return;
    int s = rowptr[row], e = rowptr[row + 1];
    for (int i = s; i < e - 1; ++i) {          // selection sort; deg ~Poisson(16)
        int mn = slots[i], mj = i;
        for (int j = i + 1; j < e; ++j) {
            int v = slots[j];
            if (v < mn) { mn = v; mj = j; }
        }
        if (mj != i) { slots[mj] = slots[i]; slots[i] = mn; }
    }
}

// ---------------- CSR build step 5: gather col/val into sorted slot order ----------------
__global__ __launch_bounds__(256) void gather_kernel(int* __restrict__ slots,
                                                     float* __restrict__ vals_s,
                                                     const int* __restrict__ ecol,
                                                     const float* __restrict__ ev, int nE) {
    int s = blockIdx.x * 256 + threadIdx.x;
    if (s >= nE) return;
    int e = slots[s];
    slots[s] = ecol[e];
    vals_s[s] = ev[e];
}

// ---------------- pull SpMM: t[row] = sum_k val[k] * h[col[k]]  (1 wave per row) ----------------
__global__ __launch_bounds__(256) void spmm_pull_kernel(const float* __restrict__ h,
                                                        const int* __restrict__ rowptr,
                                                        const int* __restrict__ cols,
                                                        const float* __restrict__ vals,
                                                        float* __restrict__ t, int n) {
    int row = blockIdx.x * 4 + (threadIdx.x >> 6);
    if (row >= n) return;
    int lane = threadIdx.x & 63;
    int s = rowptr[row], e = rowptr[row + 1];
    float2 acc = make_float2(0.f, 0.f);
    for (int k = s; k < e; ++k) {
        int c = cols[k];
        float v = vals[k];
        float2 hv = *(const float2*)&h[(size_t)c * D + lane * 2];
        acc.x += v * hv.x;
        acc.y += v * hv.y;
    }
    *(float2*)&t[(size_t)row * D + lane * 2] = acc;
}

// ---------------- O = relu(A @ W), A: n x 128, W: 128 x 128 ----------------
__global__ __launch_bounds__(256) void gemm_relu_kernel(const float* __restrict__ A,
                                                        const float* __restrict__ W,
                                                        float* __restrict__ O, int n) {
    __shared__ float ws[D * D];
    for (int i = threadIdx.x * 4; i < D * D; i += 256 * 4)
        *(float4*)&ws[i] = *(const float4*)&W[i];
    __syncthreads();

    const int cg = threadIdx.x & 7;    // 8 col groups of 16
    const int rq = threadIdx.x >> 3;   // 32 row quads
    const int row0 = blockIdx.x * 128 + rq * 4;
    const int c0 = cg * 16;

    float acc[4][16];
#pragma unroll
    for (int r = 0; r < 4; ++r)
#pragma unroll
        for (int c = 0; c < 16; ++c) acc[r][c] = 0.f;

    for (int k = 0; k < D; k += 4) {
        float4 a[4];
#pragma unroll
        for (int r = 0; r < 4; ++r) {
            int row = row0 + r;
            a[r] = (row < n) ? *(const float4*)&A[(size_t)row * D + k]
                             : make_float4(0.f, 0.f, 0.f, 0.f);
        }
#pragma unroll
        for (int kk = 0; kk < 4; ++kk) {
            const float* wrow = &ws[(k + kk) * D + c0];
            float4 w0 = *(const float4*)&wrow[0];
            float4 w1 = *(const float4*)&wrow[4];
            float4 w2 = *(const float4*)&wrow[8];
            float4 w3 = *(const float4*)&wrow[12];
#pragma unroll
            for (int r = 0; r < 4; ++r) {
                float av = (&a[r].x)[kk];
                acc[r][0]  += av * w0.x;  acc[r][1]  += av * w0.y;
                acc[r][2]  += av * w0.z;  acc[r][3]  += av * w0.w;
                acc[r][4]  += av * w1.x;  acc[r][5]  += av * w1.y;
                acc[r][6]  += av * w1.z;  acc[r][7]  += av * w1.w;
                acc[r][8]  += av * w2.x;  acc[r][9]  += av * w2.y;
                acc[r][10] += av * w2.z;  acc[r][11] += av * w2.w;
                acc[r][12] += av * w3.x;  acc[r][13] += av * w3.y;
                acc[r][14] += av * w3.z;  acc[r][15] += av * w3.w;
            }
        }
    }

#pragma unroll
    for (int r = 0; r < 4; ++r) {
        int row = row0 + r;
        if (row >= n) continue;
        float* o = &O[(size_t)row * D + c0];
#pragma unroll
        for (int g = 0; g < 4; ++g) {
            float4 v;
            v.x = fmaxf(acc[r][g * 4 + 0], 0.f);
            v.y = fmaxf(acc[r][g * 4 + 1], 0.f);
            v.z = fmaxf(acc[r][g * 4 + 2], 0.f);
            v.w = fmaxf(acc[r][g * 4 + 3], 0.f);
            *(float4*)&o[g * 4] = v;
        }
    }
}

// ---------------- out = (H @ Cls > 0) ? 1 : 0, Cls: 128 x 16 ----------------
__global__ __launch_bounds__(256) void classify_kernel(const float* __restrict__ H,
                                                       const float* __restrict__ Cls,
                                                       float* __restrict__ out, int n) {
    __shared__ float cs[D * 16];
    for (int i = threadIdx.x * 4; i < D * 16; i += 256 * 4)
        *(float4*)&cs[i] = *(const float4*)&Cls[i];
    __syncthreads();

    int row = blockIdx.x * 256 + threadIdx.x;
    if (row >= n) return;

    float acc[16];
#pragma unroll
    for (int j = 0; j < 16; ++j) acc[j] = 0.f;

    for (int k = 0; k < D; k += 4) {
        float4 h = *(const float4*)&H[(size_t)row * D + k];
#pragma unroll
        for (int kk = 0; kk < 4; ++kk) {
            float hv = (&h.x)[kk];
            const float* crow = &cs[(k + kk) * 16];
#pragma unroll
            for (int j = 0; j < 16; ++j) acc[j] += hv * crow[j];
        }
    }

    float* o = &out[(size_t)row * 16];
#pragma unroll
    for (int g = 0; g < 4; ++g) {
        float4 v;
        v.x = acc[g * 4 + 0] > 0.f ? 1.f : 0.f;
        v.y = acc[g * 4 + 1] > 0.f ? 1.f : 0.f;
        v.z = acc[g * 4 + 2] > 0.f ? 1.f : 0.f;
        v.w = acc[g * 4 + 3] > 0.f ? 1.f : 0.f;
        *(float4*)&o[g * 4] = v;
    }
}

extern "C" void kernel_launch(void* const* d_in, const int* in_sizes, int n_in,
                              void* d_out, int out_size, void* d_ws, size_t ws_size,
                              hipStream_t stream) {
    const float* x    = (const float*)d_in[0];
    const int*   erow = (const int*)d_in[1];
    const int*   ecol = (const int*)d_in[2];
    const float* ev   = (const float*)d_in[3];
    const float* w1   = (const float*)d_in[4];
    const float* w2   = (const float*)d_in[5];
    const float* cls  = (const float*)d_in[6];

    const int n  = in_sizes[0] / D;   // 100000
    const int nE = in_sizes[1];       // 1600000

    // workspace layout
    char* ws = (char*)d_ws;
    float* t      = (float*)ws;                 ws += (size_t)n * D * 4;   // 51.2 MB
    float* h      = (float*)ws;                 ws += (size_t)n * D * 4;   // 51.2 MB
    int*   deg    = (int*)ws;                   ws += (size_t)n * 4;
    int*   rowptr = (int*)ws;                   ws += (size_t)(n + 1) * 4;
    int*   fill   = (int*)ws;                   ws += (size_t)n * 4;
    int*   cols_s = (int*)ws;                   ws += (size_t)nE * 4;
    float* vals_s = (float*)ws;                 ws += (size_t)nE * 4;

    dim3 blk(256);
    dim3 egrid((nE + 255) / 256);
    dim3 ngrid((n + 255) / 256);
    dim3 sgrid((n + 3) / 4);
    dim3 ggrid((n + 127) / 128);

    // ---- CSR build (deterministic) ----
    hipMemsetAsync(deg, 0, (size_t)n * 4, stream);
    hipMemsetAsync(fill, 0, (size_t)n * 4, stream);
    hist_kernel<<<egrid, blk, 0, stream>>>(erow, deg, nE);
    scan_kernel<<<1, 1024, 0, stream>>>(deg, rowptr, n);
    place_kernel<<<egrid, blk, 0, stream>>>(erow, rowptr, fill, cols_s, nE);
    sortrow_kernel<<<ngrid, blk, 0, stream>>>(rowptr, cols_s, n);
    gather_kernel<<<egrid, blk, 0, stream>>>(cols_s, vals_s, ecol, ev, nE);

    // ---- layer 1 ----
    spmm_pull_kernel<<<sgrid, blk, 0, stream>>>(x, rowptr, cols_s, vals_s, t, n);
    gemm_relu_kernel<<<ggrid, blk, 0, stream>>>(t, w1, h, n);

    // ---- layer 2 ----
    spmm_pull_kernel<<<sgrid, blk, 0, stream>>>(h, rowptr, cols_s, vals_s, t, n);
    gemm_relu_kernel<<<ggrid, blk, 0, stream>>>(t, w2, h, n);

    // ---- classifier + hard threshold ----
    classify_kernel<<<ngrid, blk, 0, stream>>>(h, cls, (float*)d_out, n);
}

// Round 3
// 704.300 us; speedup vs baseline: 1.3768x; 1.3768x over previous
//
#include <hip/hip_runtime.h>

#define D 128

// ---------------- CSR build step 1: histogram ----------------
__global__ __launch_bounds__(256) void hist_kernel(const int* __restrict__ erow,
                                                   int* __restrict__ deg, int nE) {
    int e = blockIdx.x * 256 + threadIdx.x;
    if (e < nE) atomicAdd(&deg[erow[e]], 1);
}

// ---------------- scan phase 1: per-block (1024 elems) inclusive scan ----------------
// writes rowptr[i+1] = local inclusive scan; blocksums[b] = block total
__global__ __launch_bounds__(256) void scan1_kernel(const int* __restrict__ deg,
                                                    int* __restrict__ rowptr,
                                                    int* __restrict__ blocksums, int n) {
    __shared__ int sd[256];
    const int t = threadIdx.x;
    const int idx = blockIdx.x * 1024 + t * 4;
    int4 v = make_int4(0, 0, 0, 0);
    if (idx + 3 < n) v = *(const int4*)&deg[idx];
    else {
        if (idx + 0 < n) v.x = deg[idx + 0];
        if (idx + 1 < n) v.y = deg[idx + 1];
        if (idx + 2 < n) v.z = deg[idx + 2];
        if (idx + 3 < n) v.w = deg[idx + 3];
    }
    const int s = v.x + v.y + v.z + v.w;
    sd[t] = s;
    __syncthreads();
    for (int off = 1; off < 256; off <<= 1) {
        int tv = (t >= off) ? sd[t - off] : 0;
        __syncthreads();
        sd[t] += tv;
        __syncthreads();
    }
    const int excl = sd[t] - s;
    int a = excl + v.x, b = a + v.y, c = b + v.z, d = c + v.w;
    if (idx + 0 < n) rowptr[idx + 1] = a;
    if (idx + 1 < n) rowptr[idx + 2] = b;
    if (idx + 2 < n) rowptr[idx + 3] = c;
    if (idx + 3 < n) rowptr[idx + 4] = d;
    if (t == 255) blocksums[blockIdx.x] = sd[255];
}

// ---------------- scan phase 2: exclusive scan of block sums (nb <= 256) ----------------
__global__ __launch_bounds__(256) void scan2_kernel(int* __restrict__ blocksums, int nb) {
    __shared__ int sd[256];
    const int t = threadIdx.x;
    const int v = (t < nb) ? blocksums[t] : 0;
    sd[t] = v;
    __syncthreads();
    for (int off = 1; off < 256; off <<= 1) {
        int tv = (t >= off) ? sd[t - off] : 0;
        __syncthreads();
        sd[t] += tv;
        __syncthreads();
    }
    if (t < nb) blocksums[t] = sd[t] - v;   // exclusive
}

// ---------------- scan phase 3: add block offsets; finalize rowptr ----------------
__global__ __launch_bounds__(256) void scan3_kernel(int* __restrict__ rowptr,
                                                    const int* __restrict__ blocksums, int n) {
    int i = blockIdx.x * 256 + threadIdx.x;
    if (i < n) rowptr[i + 1] += blocksums[i >> 10];
    if (i == 0) rowptr[0] = 0;
}

// ---------------- CSR build: placement (slot order nondeterministic) ----------------
__global__ __launch_bounds__(256) void place_kernel(const int* __restrict__ erow,
                                                    const int* __restrict__ rowptr,
                                                    int* __restrict__ fill,
                                                    int* __restrict__ slots, int nE) {
    int e = blockIdx.x * 256 + threadIdx.x;
    if (e >= nE) return;
    int r = erow[e];
    int pos = rowptr[r] + atomicAdd(&fill[r], 1);
    slots[pos] = e;   // store edge index for canonical re-sort
}

// ---------------- CSR build: canonicalize (sort each row's slots by edge idx) ----------------
__global__ __launch_bounds__(256) void sortrow_kernel(const int* __restrict__ rowptr,
                                                      int* __restrict__ slots, int n) {
    int row = blockIdx.x * 256 + threadIdx.x;
    if (row >= n) return;
    int s = rowptr[row], e = rowptr[row + 1];
    for (int i = s + 1; i < e; ++i) {          // insertion sort; deg ~Poisson(16)
        int key = slots[i];
        int j = i - 1;
        while (j >= s && slots[j] > key) { slots[j + 1] = slots[j]; --j; }
        slots[j + 1] = key;
    }
}

// ---------------- CSR build: gather col/val into sorted slot order ----------------
__global__ __launch_bounds__(256) void gather_kernel(int* __restrict__ slots,
                                                     float* __restrict__ vals_s,
                                                     const int* __restrict__ ecol,
                                                     const float* __restrict__ ev, int nE) {
    int s = blockIdx.x * 256 + threadIdx.x;
    if (s >= nE) return;
    int e = slots[s];
    slots[s] = ecol[e];
    vals_s[s] = ev[e];
}

// ---------------- pull SpMM: t[row] = sum_k val[k] * h[col[k]]  (1 wave per row) ----------------
// unrolled x4: 4 independent row-gathers in flight per wave
__global__ __launch_bounds__(256) void spmm_pull_kernel(const float* __restrict__ h,
                                                        const int* __restrict__ rowptr,
                                                        const int* __restrict__ cols,
                                                        const float* __restrict__ vals,
                                                        float* __restrict__ t, int n) {
    int row = blockIdx.x * 4 + (threadIdx.x >> 6);
    if (row >= n) return;
    const int lane = threadIdx.x & 63;
    const float* hl = h + lane * 2;
    int s = rowptr[row], e = rowptr[row + 1];
    float2 acc = make_float2(0.f, 0.f);
    int k = s;
    for (; k + 4 <= e; k += 4) {
        int c0 = cols[k], c1 = cols[k + 1], c2 = cols[k + 2], c3 = cols[k + 3];
        float v0 = vals[k], v1 = vals[k + 1], v2 = vals[k + 2], v3 = vals[k + 3];
        float2 h0 = *(const float2*)&hl[(size_t)c0 * D];
        float2 h1 = *(const float2*)&hl[(size_t)c1 * D];
        float2 h2 = *(const float2*)&hl[(size_t)c2 * D];
        float2 h3 = *(const float2*)&hl[(size_t)c3 * D];
        acc.x += v0 * h0.x; acc.y += v0 * h0.y;
        acc.x += v1 * h1.x; acc.y += v1 * h1.y;
        acc.x += v2 * h2.x; acc.y += v2 * h2.y;
        acc.x += v3 * h3.x; acc.y += v3 * h3.y;
    }
    for (; k < e; ++k) {
        int c = cols[k];
        float v = vals[k];
        float2 hv = *(const float2*)&hl[(size_t)c * D];
        acc.x += v * hv.x;
        acc.y += v * hv.y;
    }
    *(float2*)&t[(size_t)row * D + lane * 2] = acc;
}

// ---------------- O = relu(A @ W), A: n x 128, W: 128 x 128 ----------------
__global__ __launch_bounds__(256) void gemm_relu_kernel(const float* __restrict__ A,
                                                        const float* __restrict__ W,
                                                        float* __restrict__ O, int n) {
    __shared__ float ws[D * D];
    for (int i = threadIdx.x * 4; i < D * D; i += 256 * 4)
        *(float4*)&ws[i] = *(const float4*)&W[i];
    __syncthreads();

    const int cg = threadIdx.x & 7;    // 8 col groups of 16
    const int rq = threadIdx.x >> 3;   // 32 row quads
    const int row0 = blockIdx.x * 128 + rq * 4;
    const int c0 = cg * 16;

    float acc[4][16];
#pragma unroll
    for (int r = 0; r < 4; ++r)
#pragma unroll
        for (int c = 0; c < 16; ++c) acc[r][c] = 0.f;

    for (int k = 0; k < D; k += 4) {
        float4 a[4];
#pragma unroll
        for (int r = 0; r < 4; ++r) {
            int row = row0 + r;
            a[r] = (row < n) ? *(const float4*)&A[(size_t)row * D + k]
                             : make_float4(0.f, 0.f, 0.f, 0.f);
        }
#pragma unroll
        for (int kk = 0; kk < 4; ++kk) {
            const float* wrow = &ws[(k + kk) * D + c0];
            float4 w0 = *(const float4*)&wrow[0];
            float4 w1 = *(const float4*)&wrow[4];
            float4 w2 = *(const float4*)&wrow[8];
            float4 w3 = *(const float4*)&wrow[12];
#pragma unroll
            for (int r = 0; r < 4; ++r) {
                float av = (&a[r].x)[kk];
                acc[r][0]  += av * w0.x;  acc[r][1]  += av * w0.y;
                acc[r][2]  += av * w0.z;  acc[r][3]  += av * w0.w;
                acc[r][4]  += av * w1.x;  acc[r][5]  += av * w1.y;
                acc[r][6]  += av * w1.z;  acc[r][7]  += av * w1.w;
                acc[r][8]  += av * w2.x;  acc[r][9]  += av * w2.y;
                acc[r][10] += av * w2.z;  acc[r][11] += av * w2.w;
                acc[r][12] += av * w3.x;  acc[r][13] += av * w3.y;
                acc[r][14] += av * w3.z;  acc[r][15] += av * w3.w;
            }
        }
    }

#pragma unroll
    for (int r = 0; r < 4; ++r) {
        int row = row0 + r;
        if (row >= n) continue;
        float* o = &O[(size_t)row * D + c0];
#pragma unroll
        for (int g = 0; g < 4; ++g) {
            float4 v;
            v.x = fmaxf(acc[r][g * 4 + 0], 0.f);
            v.y = fmaxf(acc[r][g * 4 + 1], 0.f);
            v.z = fmaxf(acc[r][g * 4 + 2], 0.f);
            v.w = fmaxf(acc[r][g * 4 + 3], 0.f);
            *(float4*)&o[g * 4] = v;
        }
    }
}

// ---------------- out = (H @ Cls > 0) ? 1 : 0, Cls: 128 x 16 ----------------
__global__ __launch_bounds__(256) void classify_kernel(const float* __restrict__ H,
                                                       const float* __restrict__ Cls,
                                                       float* __restrict__ out, int n) {
    __shared__ float cs[D * 16];
    for (int i = threadIdx.x * 4; i < D * 16; i += 256 * 4)
        *(float4*)&cs[i] = *(const float4*)&Cls[i];
    __syncthreads();

    int row = blockIdx.x * 256 + threadIdx.x;
    if (row >= n) return;

    float acc[16];
#pragma unroll
    for (int j = 0; j < 16; ++j) acc[j] = 0.f;

    for (int k = 0; k < D; k += 4) {
        float4 h = *(const float4*)&H[(size_t)row * D + k];
#pragma unroll
        for (int kk = 0; kk < 4; ++kk) {
            float hv = (&h.x)[kk];
            const float* crow = &cs[(k + kk) * 16];
#pragma unroll
            for (int j = 0; j < 16; ++j) acc[j] += hv * crow[j];
        }
    }

    float* o = &out[(size_t)row * 16];
#pragma unroll
    for (int g = 0; g < 4; ++g) {
        float4 v;
        v.x = acc[g * 4 + 0] > 0.f ? 1.f : 0.f;
        v.y = acc[g * 4 + 1] > 0.f ? 1.f : 0.f;
        v.z = acc[g * 4 + 2] > 0.f ? 1.f : 0.f;
        v.w = acc[g * 4 + 3] > 0.f ? 1.f : 0.f;
        *(float4*)&o[g * 4] = v;
    }
}

extern "C" void kernel_launch(void* const* d_in, const int* in_sizes, int n_in,
                              void* d_out, int out_size, void* d_ws, size_t ws_size,
                              hipStream_t stream) {
    const float* x    = (const float*)d_in[0];
    const int*   erow = (const int*)d_in[1];
    const int*   ecol = (const int*)d_in[2];
    const float* ev   = (const float*)d_in[3];
    const float* w1   = (const float*)d_in[4];
    const float* w2   = (const float*)d_in[5];
    const float* cls  = (const float*)d_in[6];

    const int n  = in_sizes[0] / D;   // 100000
    const int nE = in_sizes[1];       // 1600000

    // workspace layout
    char* ws = (char*)d_ws;
    float* t      = (float*)ws;                 ws += (size_t)n * D * 4;   // 51.2 MB
    float* h      = (float*)ws;                 ws += (size_t)n * D * 4;   // 51.2 MB
    int*   deg    = (int*)ws;                   ws += (size_t)n * 4;
    int*   rowptr = (int*)ws;                   ws += (size_t)(n + 1) * 4;
    int*   fill   = (int*)ws;                   ws += (size_t)n * 4;
    int*   cols_s = (int*)ws;                   ws += (size_t)nE * 4;
    float* vals_s = (float*)ws;                 ws += (size_t)nE * 4;
    int*   bsums  = (int*)ws;                   ws += 256 * 4;

    const int nb = (n + 1023) / 1024;   // 98, must be <= 256

    dim3 blk(256);
    dim3 egrid((nE + 255) / 256);
    dim3 ngrid((n + 255) / 256);
    dim3 sgrid((n + 3) / 4);
    dim3 ggrid((n + 127) / 128);

    // ---- CSR build (deterministic) ----
    hipMemsetAsync(deg, 0, (size_t)n * 4, stream);
    hipMemsetAsync(fill, 0, (size_t)n * 4, stream);
    hist_kernel<<<egrid, blk, 0, stream>>>(erow, deg, nE);
    scan1_kernel<<<nb, blk, 0, stream>>>(deg, rowptr, bsums, n);
    scan2_kernel<<<1, blk, 0, stream>>>(bsums, nb);
    scan3_kernel<<<ngrid, blk, 0, stream>>>(rowptr, bsums, n);
    place_kernel<<<egrid, blk, 0, stream>>>(erow, rowptr, fill, cols_s, nE);
    sortrow_kernel<<<ngrid, blk, 0, stream>>>(rowptr, cols_s, n);
    gather_kernel<<<egrid, blk, 0, stream>>>(cols_s, vals_s, ecol, ev, nE);

    // ---- layer 1 ----
    spmm_pull_kernel<<<sgrid, blk, 0, stream>>>(x, rowptr, cols_s, vals_s, t, n);
    gemm_relu_kernel<<<ggrid, blk, 0, stream>>>(t, w1, h, n);

    // ---- layer 2 ----
    spmm_pull_kernel<<<sgrid, blk, 0, stream>>>(h, rowptr, cols_s, vals_s, t, n);
    gemm_relu_kernel<<<ggrid, blk, 0, stream>>>(t, w2, h, n);

    // ---- classifier + hard threshold ----
    classify_kernel<<<ngrid, blk, 0, stream>>>(h, cls, (float*)d_out, n);
}

// Round 4
// 663.422 us; speedup vs baseline: 1.4616x; 1.0616x over previous
//
#include <hip/hip_runtime.h>
#include <climits>

#define D 128

// ---------------- CSR build step 1: histogram ----------------
__global__ __launch_bounds__(256) void hist_kernel(const int* __restrict__ erow,
                                                   int* __restrict__ deg, int nE) {
    int e = blockIdx.x * 256 + threadIdx.x;
    if (e < nE) atomicAdd(&deg[erow[e]], 1);
}

// ---------------- scan phase 1: per-block (1024 elems) inclusive scan ----------------
__global__ __launch_bounds__(256) void scan1_kernel(const int* __restrict__ deg,
                                                    int* __restrict__ rowptr,
                                                    int* __restrict__ blocksums, int n) {
    __shared__ int sd[256];
    const int t = threadIdx.x;
    const int idx = blockIdx.x * 1024 + t * 4;
    int4 v = make_int4(0, 0, 0, 0);
    if (idx + 3 < n) v = *(const int4*)&deg[idx];
    else {
        if (idx + 0 < n) v.x = deg[idx + 0];
        if (idx + 1 < n) v.y = deg[idx + 1];
        if (idx + 2 < n) v.z = deg[idx + 2];
        if (idx + 3 < n) v.w = deg[idx + 3];
    }
    const int s = v.x + v.y + v.z + v.w;
    sd[t] = s;
    __syncthreads();
    for (int off = 1; off < 256; off <<= 1) {
        int tv = (t >= off) ? sd[t - off] : 0;
        __syncthreads();
        sd[t] += tv;
        __syncthreads();
    }
    const int excl = sd[t] - s;
    int a = excl + v.x, b = a + v.y, c = b + v.z, d = c + v.w;
    if (idx + 0 < n) rowptr[idx + 1] = a;
    if (idx + 1 < n) rowptr[idx + 2] = b;
    if (idx + 2 < n) rowptr[idx + 3] = c;
    if (idx + 3 < n) rowptr[idx + 4] = d;
    if (t == 255) blocksums[blockIdx.x] = sd[255];
}

// ---------------- scan phase 2: exclusive scan of block sums (nb <= 256) ----------------
__global__ __launch_bounds__(256) void scan2_kernel(int* __restrict__ blocksums, int nb) {
    __shared__ int sd[256];
    const int t = threadIdx.x;
    const int v = (t < nb) ? blocksums[t] : 0;
    sd[t] = v;
    __syncthreads();
    for (int off = 1; off < 256; off <<= 1) {
        int tv = (t >= off) ? sd[t - off] : 0;
        __syncthreads();
        sd[t] += tv;
        __syncthreads();
    }
    if (t < nb) blocksums[t] = sd[t] - v;   // exclusive
}

// ---------------- scan phase 3: add block offsets; finalize rowptr ----------------
__global__ __launch_bounds__(256) void scan3_kernel(int* __restrict__ rowptr,
                                                    const int* __restrict__ blocksums, int n) {
    int i = blockIdx.x * 256 + threadIdx.x;
    if (i < n) rowptr[i + 1] += blocksums[i >> 10];
    if (i == 0) rowptr[0] = 0;
}

// ---------------- CSR build: placement (slot order nondeterministic) ----------------
__global__ __launch_bounds__(256) void place_kernel(const int* __restrict__ erow,
                                                    const int* __restrict__ rowptr,
                                                    int* __restrict__ fill,
                                                    int* __restrict__ slots, int nE) {
    int e = blockIdx.x * 256 + threadIdx.x;
    if (e >= nE) return;
    int r = erow[e];
    int pos = rowptr[r] + atomicAdd(&fill[r], 1);
    slots[pos] = e;   // edge index; canonicalized by sortrow_wave
}

// ---- canonicalize + gather: wave rank-sort of each row's edge indices, then fetch col/val ----
// one 64-lane wave per row; in-place on slots (=cols_s), writes vals_s
__global__ __launch_bounds__(256) void sortrow_wave_kernel(const int* __restrict__ rowptr,
                                                           int* __restrict__ cols_s,
                                                           float* __restrict__ vals_s,
                                                           const int* __restrict__ ecol,
                                                           const float* __restrict__ ev, int n) {
    int row = blockIdx.x * 4 + (threadIdx.x >> 6);
    if (row >= n) return;
    const int lane = threadIdx.x & 63;
    const int s = rowptr[row], e = rowptr[row + 1];
    const int deg = e - s;
    if (deg <= 0) return;
    if (deg <= 64) {
        int v = (lane < deg) ? cols_s[s + lane] : INT_MAX;
        int rank = 0;
        for (int i = 0; i < deg; ++i) {
            int vi = __shfl(v, i);
            rank += (vi < v) ? 1 : 0;
        }
        if (lane < deg) {                       // wave-lockstep: all reads precede writes
            cols_s[s + rank] = ecol[v];
            vals_s[s + rank] = ev[v];
        }
    } else if (lane == 0) {                     // ~never (deg ~ Poisson(16))
        for (int i = s + 1; i < e; ++i) {
            int key = cols_s[i];
            int j = i - 1;
            while (j >= s && cols_s[j] > key) { cols_s[j + 1] = cols_s[j]; --j; }
            cols_s[j + 1] = key;
        }
        for (int i = s; i < e; ++i) {
            int eidx = cols_s[i];
            cols_s[i] = ecol[eidx];
            vals_s[i] = ev[eidx];
        }
    }
}

// ---------------- pull SpMM: t[row] = sum_k val[k] * h[col[k]] ----------------
// 32 lanes x float4 per row; 2 rows per wave; unroll 4 -> 8 gathers in flight/wave
__global__ __launch_bounds__(256) void spmm_pull_kernel(const float* __restrict__ h,
                                                        const int* __restrict__ rowptr,
                                                        const int* __restrict__ cols,
                                                        const float* __restrict__ vals,
                                                        float* __restrict__ t, int n) {
    int r = blockIdx.x * 8 + (threadIdx.x >> 5);
    if (r >= n) return;
    const int l = threadIdx.x & 31;
    const float4* hl = (const float4*)h + l;
    int s = rowptr[r], e = rowptr[r + 1];
    float4 acc = make_float4(0.f, 0.f, 0.f, 0.f);
    int k = s;
    for (; k + 4 <= e; k += 4) {
        int c0 = cols[k], c1 = cols[k + 1], c2 = cols[k + 2], c3 = cols[k + 3];
        float v0 = vals[k], v1 = vals[k + 1], v2 = vals[k + 2], v3 = vals[k + 3];
        float4 h0 = hl[(size_t)c0 * 32];
        float4 h1 = hl[(size_t)c1 * 32];
        float4 h2 = hl[(size_t)c2 * 32];
        float4 h3 = hl[(size_t)c3 * 32];
        acc.x += v0 * h0.x; acc.y += v0 * h0.y; acc.z += v0 * h0.z; acc.w += v0 * h0.w;
        acc.x += v1 * h1.x; acc.y += v1 * h1.y; acc.z += v1 * h1.z; acc.w += v1 * h1.w;
        acc.x += v2 * h2.x; acc.y += v2 * h2.y; acc.z += v2 * h2.z; acc.w += v2 * h2.w;
        acc.x += v3 * h3.x; acc.y += v3 * h3.y; acc.z += v3 * h3.z; acc.w += v3 * h3.w;
    }
    for (; k < e; ++k) {
        int c = cols[k];
        float v = vals[k];
        float4 hv = hl[(size_t)c * 32];
        acc.x += v * hv.x; acc.y += v * hv.y; acc.z += v * hv.z; acc.w += v * hv.w;
    }
    ((float4*)t)[(size_t)r * 32 + l] = acc;
}

// ---------------- O = relu(A @ W), A: n x 128, W: 128 x 128 ----------------
__global__ __launch_bounds__(256) void gemm_relu_kernel(const float* __restrict__ A,
                                                        const float* __restrict__ W,
                                                        float* __restrict__ O, int n) {
    __shared__ float ws[D * D];
    for (int i = threadIdx.x * 4; i < D * D; i += 256 * 4)
        *(float4*)&ws[i] = *(const float4*)&W[i];
    __syncthreads();

    const int cg = threadIdx.x & 7;    // 8 col groups of 16
    const int rq = threadIdx.x >> 3;   // 32 row quads
    const int row0 = blockIdx.x * 128 + rq * 4;
    const int c0 = cg * 16;

    float acc[4][16];
#pragma unroll
    for (int r = 0; r < 4; ++r)
#pragma unroll
        for (int c = 0; c < 16; ++c) acc[r][c] = 0.f;

    for (int k = 0; k < D; k += 4) {
        float4 a[4];
#pragma unroll
        for (int r = 0; r < 4; ++r) {
            int row = row0 + r;
            a[r] = (row < n) ? *(const float4*)&A[(size_t)row * D + k]
                             : make_float4(0.f, 0.f, 0.f, 0.f);
        }
#pragma unroll
        for (int kk = 0; kk < 4; ++kk) {
            const float* wrow = &ws[(k + kk) * D + c0];
            float4 w0 = *(const float4*)&wrow[0];
            float4 w1 = *(const float4*)&wrow[4];
            float4 w2 = *(const float4*)&wrow[8];
            float4 w3 = *(const float4*)&wrow[12];
#pragma unroll
            for (int r = 0; r < 4; ++r) {
                float av = (&a[r].x)[kk];
                acc[r][0]  += av * w0.x;  acc[r][1]  += av * w0.y;
                acc[r][2]  += av * w0.z;  acc[r][3]  += av * w0.w;
                acc[r][4]  += av * w1.x;  acc[r][5]  += av * w1.y;
                acc[r][6]  += av * w1.z;  acc[r][7]  += av * w1.w;
                acc[r][8]  += av * w2.x;  acc[r][9]  += av * w2.y;
                acc[r][10] += av * w2.z;  acc[r][11] += av * w2.w;
                acc[r][12] += av * w3.x;  acc[r][13] += av * w3.y;
                acc[r][14] += av * w3.z;  acc[r][15] += av * w3.w;
            }
        }
    }

#pragma unroll
    for (int r = 0; r < 4; ++r) {
        int row = row0 + r;
        if (row >= n) continue;
        float* o = &O[(size_t)row * D + c0];
#pragma unroll
        for (int g = 0; g < 4; ++g) {
            float4 v;
            v.x = fmaxf(acc[r][g * 4 + 0], 0.f);
            v.y = fmaxf(acc[r][g * 4 + 1], 0.f);
            v.z = fmaxf(acc[r][g * 4 + 2], 0.f);
            v.w = fmaxf(acc[r][g * 4 + 3], 0.f);
            *(float4*)&o[g * 4] = v;
        }
    }
}

// ---------------- out = (H @ Cls > 0) ? 1 : 0, Cls: 128 x 16 ----------------
__global__ __launch_bounds__(256) void classify_kernel(const float* __restrict__ H,
                                                       const float* __restrict__ Cls,
                                                       float* __restrict__ out, int n) {
    __shared__ float cs[D * 16];
    for (int i = threadIdx.x * 4; i < D * 16; i += 256 * 4)
        *(float4*)&cs[i] = *(const float4*)&Cls[i];
    __syncthreads();

    int row = blockIdx.x * 256 + threadIdx.x;
    if (row >= n) return;

    float acc[16];
#pragma unroll
    for (int j = 0; j < 16; ++j) acc[j] = 0.f;

    for (int k = 0; k < D; k += 4) {
        float4 h = *(const float4*)&H[(size_t)row * D + k];
#pragma unroll
        for (int kk = 0; kk < 4; ++kk) {
            float hv = (&h.x)[kk];
            const float* crow = &cs[(k + kk) * 16];
#pragma unroll
            for (int j = 0; j < 16; ++j) acc[j] += hv * crow[j];
        }
    }

    float* o = &out[(size_t)row * 16];
#pragma unroll
    for (int g = 0; g < 4; ++g) {
        float4 v;
        v.x = acc[g * 4 + 0] > 0.f ? 1.f : 0.f;
        v.y = acc[g * 4 + 1] > 0.f ? 1.f : 0.f;
        v.z = acc[g * 4 + 2] > 0.f ? 1.f : 0.f;
        v.w = acc[g * 4 + 3] > 0.f ? 1.f : 0.f;
        *(float4*)&o[g * 4] = v;
    }
}

extern "C" void kernel_launch(void* const* d_in, const int* in_sizes, int n_in,
                              void* d_out, int out_size, void* d_ws, size_t ws_size,
                              hipStream_t stream) {
    const float* x    = (const float*)d_in[0];
    const int*   erow = (const int*)d_in[1];
    const int*   ecol = (const int*)d_in[2];
    const float* ev   = (const float*)d_in[3];
    const float* w1   = (const float*)d_in[4];
    const float* w2   = (const float*)d_in[5];
    const float* cls  = (const float*)d_in[6];

    const int n  = in_sizes[0] / D;   // 100000
    const int nE = in_sizes[1];       // 1600000

    // workspace layout
    char* ws = (char*)d_ws;
    float* t      = (float*)ws;                 ws += (size_t)n * D * 4;   // 51.2 MB
    float* h      = (float*)ws;                 ws += (size_t)n * D * 4;   // 51.2 MB
    int*   deg    = (int*)ws;                   ws += (size_t)n * 4;
    int*   rowptr = (int*)ws;                   ws += (size_t)(n + 1) * 4;
    int*   fill   = (int*)ws;                   ws += (size_t)n * 4;
    int*   cols_s = (int*)ws;                   ws += (size_t)nE * 4;      // slots -> cols
    float* vals_s = (float*)ws;                 ws += (size_t)nE * 4;
    int*   bsums  = (int*)ws;                   ws += 256 * 4;

    const int nb = (n + 1023) / 1024;   // 98 <= 256

    dim3 blk(256);
    dim3 egrid((nE + 255) / 256);
    dim3 ngrid((n + 255) / 256);
    dim3 wgrid((n + 3) / 4);      // 1 wave per row kernels
    dim3 sgrid((n + 7) / 8);      // spmm: 8 rows per block
    dim3 ggrid((n + 127) / 128);

    // ---- CSR build (deterministic) ----
    hipMemsetAsync(deg, 0, (size_t)n * 4, stream);
    hipMemsetAsync(fill, 0, (size_t)n * 4, stream);
    hist_kernel<<<egrid, blk, 0, stream>>>(erow, deg, nE);
    scan1_kernel<<<nb, blk, 0, stream>>>(deg, rowptr, bsums, n);
    scan2_kernel<<<1, blk, 0, stream>>>(bsums, nb);
    scan3_kernel<<<ngrid, blk, 0, stream>>>(rowptr, bsums, n);
    place_kernel<<<egrid, blk, 0, stream>>>(erow, rowptr, fill, cols_s, nE);
    sortrow_wave_kernel<<<wgrid, blk, 0, stream>>>(rowptr, cols_s, vals_s, ecol, ev, n);

    // ---- layer 1 ----
    spmm_pull_kernel<<<sgrid, blk, 0, stream>>>(x, rowptr, cols_s, vals_s, t, n);
    gemm_relu_kernel<<<ggrid, blk, 0, stream>>>(t, w1, h, n);

    // ---- layer 2 ----
    spmm_pull_kernel<<<sgrid, blk, 0, stream>>>(h, rowptr, cols_s, vals_s, t, n);
    gemm_relu_kernel<<<ggrid, blk, 0, stream>>>(t, w2, h, n);

    // ---- classifier + hard threshold ----
    classify_kernel<<<ngrid, blk, 0, stream>>>(h, cls, (float*)d_out, n);
}